// Round 2
// baseline (440.537 us; speedup 1.0000x reference)
//
#include <hip/hip_runtime.h>
#include <hip/hip_bf16.h>

#define IN_C  128
#define HID_C 64
#define OUT_C 32
#define NEG_SLOPE 0.2f

// ---------------------------------------------------------------------------
// Kernel 1: deg[i] = 1 (self-loop pre-counted)
// ---------------------------------------------------------------------------
__global__ void init_deg_kernel(int* __restrict__ deg, int n) {
    int i = blockIdx.x * blockDim.x + threadIdx.x;
    if (i < n) deg[i] = 1;
}

// ---------------------------------------------------------------------------
// Kernel 2: histogram of edge destinations
// ---------------------------------------------------------------------------
__global__ void hist_kernel(const int* __restrict__ ei_dst, int E,
                            int* __restrict__ deg) {
    int i = blockIdx.x * blockDim.x + threadIdx.x;
    if (i < E) atomicAdd(deg + ei_dst[i], 1);
}

// ---------------------------------------------------------------------------
// Kernel 3: single-block exclusive scan deg -> rowptr (n+1) and cursor (n)
// 1024 threads, each owns a contiguous chunk; Hillis-Steele across threads.
// ---------------------------------------------------------------------------
__global__ __launch_bounds__(1024) void scan_kernel(
    const int* __restrict__ deg, int* __restrict__ rowptr,
    int* __restrict__ cursor, int n)
{
    __shared__ int tsum[1024];
    const int t = threadIdx.x;
    const int chunk = (n + 1023) / 1024;
    const int start = t * chunk;
    const int end   = (start + chunk < n) ? start + chunk : n;

    int s = 0;
    for (int i = start; i < end; ++i) s += deg[i];
    tsum[t] = s;
    __syncthreads();
#pragma unroll
    for (int off = 1; off < 1024; off <<= 1) {
        int add = (t >= off) ? tsum[t - off] : 0;
        __syncthreads();
        tsum[t] += add;
        __syncthreads();
    }
    int run = (t == 0) ? 0 : tsum[t - 1];
    for (int i = start; i < end; ++i) {
        rowptr[i] = run;
        cursor[i] = run;
        run += deg[i];
    }
    if (t == 0) rowptr[n] = tsum[1023];
}

// ---------------------------------------------------------------------------
// Kernel 4: h = x @ W per node + attention logits. One wave per node.
// x row held in 2 regs/lane; k-broadcast via v_readlane (no LDS, no barrier).
// ---------------------------------------------------------------------------
__device__ __forceinline__ float lane_bcast(float v, int k) {
    return __int_as_float(__builtin_amdgcn_readlane(__float_as_int(v), k));
}

__global__ __launch_bounds__(256) void node_gemm_kernel(
    const float* __restrict__ x, const float* __restrict__ W,
    const float* __restrict__ att_src, const float* __restrict__ att_dst,
    float* __restrict__ h, float* __restrict__ a_src, float* __restrict__ a_dst,
    int n_nodes)
{
    const int wv   = threadIdx.x >> 6;
    const int lane = threadIdx.x & 63;
    const int node = blockIdx.x * 4 + wv;
    if (node >= n_nodes) return;

    const float* xr = x + (long)node * IN_C;
    const float xv0 = xr[lane];
    const float xv1 = xr[lane + 64];

    float acc = 0.0f;
#pragma unroll
    for (int k = 0; k < 64; ++k)
        acc = fmaf(lane_bcast(xv0, k), W[k * HID_C + lane], acc);
#pragma unroll
    for (int k = 0; k < 64; ++k)
        acc = fmaf(lane_bcast(xv1, k), W[(64 + k) * HID_C + lane], acc);

    h[(long)node * HID_C + lane] = acc;

    float vs = acc * att_src[lane];
    float vd = acc * att_dst[lane];
#pragma unroll
    for (int off = 32; off > 0; off >>= 1) {
        vs += __shfl_xor(vs, off, 64);
        vd += __shfl_xor(vd, off, 64);
    }
    if (lane == 0) {
        a_src[node] = vs;
        a_dst[node] = vd;
    }
}

// ---------------------------------------------------------------------------
// Kernel 5: bucket-fill sorted source ids (order within bucket arbitrary)
// ---------------------------------------------------------------------------
__global__ void fill_kernel(const int* __restrict__ ei, int E, int n_nodes,
                            int* __restrict__ cursor, int* __restrict__ srt)
{
    long i = (long)blockIdx.x * blockDim.x + threadIdx.x;
    long total = (long)E + n_nodes;
    if (i >= total) return;
    int s, d;
    if (i < E) { s = ei[i]; d = ei[E + i]; }
    else       { s = d = (int)(i - E); }
    int pos = atomicAdd(cursor + d, 1);
    srt[pos] = s;
}

// ---------------------------------------------------------------------------
// Kernel 6: fused aggregation + softmax-normalize + bias/relu + final linear.
// One wave per destination node, lane = hidden channel; register accumulate.
// alpha normalization factored: out = (sum w*h) / (sum w).
// ---------------------------------------------------------------------------
__global__ __launch_bounds__(256) void agg_kernel(
    const int* __restrict__ rowptr, const int* __restrict__ srt,
    const float* __restrict__ h,
    const float* __restrict__ a_src, const float* __restrict__ a_dst,
    const float* __restrict__ bias_conv,
    const float* __restrict__ W_lin, const float* __restrict__ b_lin,
    float* __restrict__ out, int n_nodes)
{
    __shared__ float v[4][HID_C];
    const int wv   = threadIdx.x >> 6;
    const int lane = threadIdx.x & 63;
    const int node = blockIdx.x * 4 + wv;
    const bool valid = node < n_nodes;

    float val = 0.0f;
    if (valid) {
        const int beg = rowptr[node];
        const int fin = rowptr[node + 1];
        const float ad = a_dst[node];
        float acc = 0.0f, den = 0.0f;
        int s = (beg < fin) ? srt[beg] : 0;
        for (int j = beg; j < fin; ++j) {
            int snext = (j + 1 < fin) ? srt[j + 1] : 0;   // prefetch
            float as = a_src[s];
            float hv = h[(long)s * HID_C + lane];
            float e = as + ad;
            e = (e >= 0.0f) ? e : NEG_SLOPE * e;
            float w = __expf(e);
            den += w;
            acc = fmaf(w, hv, acc);
            s = snext;
        }
        val = acc / (den + 1e-16f) + bias_conv[lane];
        val = (val > 0.0f) ? val : 0.0f;
    }
    v[wv][lane] = val;
    __syncthreads();

    if (valid && lane < OUT_C) {
        float o = b_lin[lane];
#pragma unroll
        for (int c = 0; c < HID_C; ++c)
            o = fmaf(v[wv][c], W_lin[c * OUT_C + lane], o);
        out[(long)node * OUT_C + lane] = o;
    }
}

// ---------------------------------------------------------------------------
extern "C" void kernel_launch(void* const* d_in, const int* in_sizes, int n_in,
                              void* d_out, int out_size, void* d_ws, size_t ws_size,
                              hipStream_t stream) {
    const float* x         = (const float*)d_in[0];
    const int*   ei        = (const int*)d_in[1];
    const float* W         = (const float*)d_in[2];
    const float* att_src   = (const float*)d_in[3];
    const float* att_dst   = (const float*)d_in[4];
    const float* bias_conv = (const float*)d_in[5];
    const float* W_lin     = (const float*)d_in[6];
    const float* b_lin     = (const float*)d_in[7];
    float*       out       = (float*)d_out;

    const int n_nodes = in_sizes[0] / IN_C;     // 50000
    const int E       = in_sizes[1] / 2;        // 800000
    const long total_edges = (long)E + n_nodes; // incl. self-loops

    // workspace layout
    float* ws    = (float*)d_ws;
    float* h     = ws;                                   // N*64 f
    float* a_src = h     + (long)n_nodes * HID_C;        // N f
    float* a_dst = a_src + n_nodes;                      // N f
    int*   deg    = (int*)(a_dst + n_nodes);             // N i
    int*   rowptr = deg    + n_nodes;                    // N+1 i
    int*   cursor = rowptr + n_nodes + 1;                // N i
    int*   srt    = cursor + n_nodes;                    // E+N i

    // 1) deg = 1 (self loops)
    init_deg_kernel<<<(n_nodes + 255) / 256, 256, 0, stream>>>(deg, n_nodes);

    // 2) histogram over real edge destinations
    hist_kernel<<<(E + 255) / 256, 256, 0, stream>>>(ei + E, E, deg);

    // 3) scan -> rowptr, cursor
    scan_kernel<<<1, 1024, 0, stream>>>(deg, rowptr, cursor, n_nodes);

    // 4) node GEMM + logits (independent of 1-3)
    node_gemm_kernel<<<(n_nodes + 3) / 4, 256, 0, stream>>>(
        x, W, att_src, att_dst, h, a_src, a_dst, n_nodes);

    // 5) bucket fill
    fill_kernel<<<(int)((total_edges + 255) / 256), 256, 0, stream>>>(
        ei, E, n_nodes, cursor, srt);

    // 6) fused aggregation + epilogue
    agg_kernel<<<(n_nodes + 3) / 4, 256, 0, stream>>>(
        rowptr, srt, h, a_src, a_dst, bias_conv, W_lin, b_lin, out, n_nodes);
}

// Round 3
// 270.287 us; speedup vs baseline: 1.6299x; 1.6299x over previous
//
#include <hip/hip_runtime.h>
#include <hip/hip_bf16.h>

#define IN_C  128
#define HID_C 64
#define OUT_C 32
#define NEG_SLOPE 0.2f

// ---------------------------------------------------------------------------
// Kernel 1: deg[i] = 1 (self-loop pre-counted)
// ---------------------------------------------------------------------------
__global__ void init_deg_kernel(int* __restrict__ deg, int n) {
    int i = blockIdx.x * blockDim.x + threadIdx.x;
    if (i < n) deg[i] = 1;
}

// ---------------------------------------------------------------------------
// Kernel 2: histogram of edge destinations
// ---------------------------------------------------------------------------
__global__ void hist_kernel(const int* __restrict__ ei_dst, int E,
                            int* __restrict__ deg) {
    int i = blockIdx.x * blockDim.x + threadIdx.x;
    if (i < E) atomicAdd(deg + ei_dst[i], 1);
}

// ---------------------------------------------------------------------------
// Scan phase A: per-block (1024-wide) exclusive scan, emit block sums
// ---------------------------------------------------------------------------
__global__ __launch_bounds__(1024) void scan1_kernel(
    const int* __restrict__ deg, int* __restrict__ rowptr,
    int* __restrict__ bsum, int n)
{
    __shared__ int sh[1024];
    const int t = threadIdx.x;
    const int i = blockIdx.x * 1024 + t;
    int val = (i < n) ? deg[i] : 0;
    sh[t] = val;
    __syncthreads();
#pragma unroll
    for (int off = 1; off < 1024; off <<= 1) {
        int add = (t >= off) ? sh[t - off] : 0;
        __syncthreads();
        sh[t] += add;
        __syncthreads();
    }
    if (i < n) rowptr[i] = sh[t] - val;       // exclusive
    if (t == 1023) bsum[blockIdx.x] = sh[1023];
}

// ---------------------------------------------------------------------------
// Scan phase B: single wave scans the block sums (nb <= 64)
// ---------------------------------------------------------------------------
__global__ __launch_bounds__(64) void scan2_kernel(
    const int* __restrict__ bsum, int* __restrict__ boff, int nb)
{
    const int t = threadIdx.x;
    int v = (t < nb) ? bsum[t] : 0;
    int incl = v;
#pragma unroll
    for (int off = 1; off < 64; off <<= 1) {
        int u = __shfl_up(incl, off, 64);
        if (t >= off) incl += u;
    }
    boff[t] = incl - v;                       // exclusive
}

// ---------------------------------------------------------------------------
// Scan phase C: add block offsets, mirror into cursor, cap rowptr[n]
// ---------------------------------------------------------------------------
__global__ void scan3_kernel(int* __restrict__ rowptr, int* __restrict__ cursor,
                             const int* __restrict__ boff, int n, int total)
{
    int i = blockIdx.x * blockDim.x + threadIdx.x;
    if (i < n) {
        int r = rowptr[i] + boff[i >> 10];
        rowptr[i] = r;
        cursor[i] = r;
    }
    if (i == 0) rowptr[n] = total;
}

// ---------------------------------------------------------------------------
// Kernel 4: h = x @ W per node + attention logits; h stored as bf16.
// W column for this lane preloaded into 128 VGPRs once per wave; grid-stride
// over node PAIRS (two independent FMA chains -> better VALU packing).
// ---------------------------------------------------------------------------
__device__ __forceinline__ float lane_bcast(float v, int k) {
    return __int_as_float(__builtin_amdgcn_readlane(__float_as_int(v), k));
}

__global__ __launch_bounds__(256) void node_gemm_kernel(
    const float* __restrict__ x, const float* __restrict__ W,
    const float* __restrict__ att_src, const float* __restrict__ att_dst,
    __hip_bfloat16* __restrict__ hb,
    float* __restrict__ a_src, float* __restrict__ a_dst,
    int n_nodes)
{
    const int lane = threadIdx.x & 63;
    const int gwave = (blockIdx.x * 256 + threadIdx.x) >> 6;
    const int nwaves = gridDim.x * 4;

    float wr[IN_C];
#pragma unroll
    for (int k = 0; k < IN_C; ++k) wr[k] = W[k * HID_C + lane];
    const float asl = att_src[lane];
    const float adl = att_dst[lane];

    for (int base = gwave * 2; base < n_nodes; base += nwaves * 2) {
        const int n0 = base;
        const int n1 = base + 1;
        const bool v1 = n1 < n_nodes;
        const float* x0 = x + (long)n0 * IN_C;
        const float* x1 = x + (long)(v1 ? n1 : n0) * IN_C;
        const float a0 = x0[lane], b0 = x0[lane + 64];
        const float a1 = x1[lane], b1 = x1[lane + 64];

        float acc0 = 0.f, acc1 = 0.f, acc0b = 0.f, acc1b = 0.f;
#pragma unroll
        for (int k = 0; k < 64; ++k) {
            acc0  = fmaf(lane_bcast(a0, k), wr[k],      acc0);
            acc1  = fmaf(lane_bcast(a1, k), wr[k],      acc1);
            acc0b = fmaf(lane_bcast(b0, k), wr[64 + k], acc0b);
            acc1b = fmaf(lane_bcast(b1, k), wr[64 + k], acc1b);
        }
        const float h0 = acc0 + acc0b;
        const float h1 = acc1 + acc1b;

        hb[(long)n0 * HID_C + lane] = __float2bfloat16(h0);
        if (v1) hb[(long)n1 * HID_C + lane] = __float2bfloat16(h1);

        float vs0 = h0 * asl, vd0 = h0 * adl;
        float vs1 = h1 * asl, vd1 = h1 * adl;
#pragma unroll
        for (int off = 32; off > 0; off >>= 1) {
            vs0 += __shfl_xor(vs0, off, 64);
            vd0 += __shfl_xor(vd0, off, 64);
            vs1 += __shfl_xor(vs1, off, 64);
            vd1 += __shfl_xor(vd1, off, 64);
        }
        if (lane == 0) {
            a_src[n0] = vs0; a_dst[n0] = vd0;
            if (v1) { a_src[n1] = vs1; a_dst[n1] = vd1; }
        }
    }
}

// ---------------------------------------------------------------------------
// Kernel 5: bucket-fill sorted source ids
// ---------------------------------------------------------------------------
__global__ void fill_kernel(const int* __restrict__ ei, int E, int n_nodes,
                            int* __restrict__ cursor, int* __restrict__ srt)
{
    long i = (long)blockIdx.x * blockDim.x + threadIdx.x;
    long total = (long)E + n_nodes;
    if (i >= total) return;
    int s, d;
    if (i < E) { s = ei[i]; d = ei[E + i]; }
    else       { s = d = (int)(i - E); }
    int pos = atomicAdd(cursor + d, 1);
    srt[pos] = s;
}

// ---------------------------------------------------------------------------
// Kernel 6: fused aggregation + softmax-normalize + bias/relu + final linear.
// One wave per dst node. lane = g*16 + l: g = edge slot (4 edges/iter),
// l = channel quad (channels 4l..4l+3, bf16 ushort4 load = 8B/lane).
// ---------------------------------------------------------------------------
__device__ __forceinline__ float bf2f(unsigned short u) {
    return __uint_as_float(((unsigned int)u) << 16);
}

__global__ __launch_bounds__(256) void agg_kernel(
    const int* __restrict__ rowptr, const int* __restrict__ srt,
    const __hip_bfloat16* __restrict__ hb,
    const float* __restrict__ a_src, const float* __restrict__ a_dst,
    const float* __restrict__ bias_conv,
    const float* __restrict__ W_lin, const float* __restrict__ b_lin,
    float* __restrict__ out, int n_nodes)
{
    __shared__ float v[4][HID_C];
    const int wv   = threadIdx.x >> 6;
    const int lane = threadIdx.x & 63;
    const int g    = lane >> 4;     // edge slot 0..3
    const int l    = lane & 15;     // channel quad
    const int node = blockIdx.x * 4 + wv;
    const bool valid = node < n_nodes;

    if (valid) {
        const int beg = rowptr[node];
        const int fin = rowptr[node + 1];
        const float ad = a_dst[node];
        float ax = 0.f, ay = 0.f, az = 0.f, aw = 0.f, den = 0.f;

        for (int j = beg; j < fin; j += 4) {
            const int  jg  = j + g;
            const bool act = jg < fin;
            const int  s   = act ? srt[jg] : srt[beg];   // deg>=1 (self loop)
            const float as = a_src[s];
            const ushort4 hv = *(const ushort4*)((const unsigned short*)hb
                                                 + (long)s * HID_C + 4 * l);
            float e = as + ad;
            e = (e >= 0.f) ? e : NEG_SLOPE * e;
            const float w = act ? __expf(e) : 0.f;
            den += w;
            ax = fmaf(w, bf2f(hv.x), ax);
            ay = fmaf(w, bf2f(hv.y), ay);
            az = fmaf(w, bf2f(hv.z), az);
            aw = fmaf(w, bf2f(hv.w), aw);
        }
        // reduce across the 4 edge slots (lanes l, l+16, l+32, l+48)
#pragma unroll
        for (int off = 16; off <= 32; off <<= 1) {
            ax  += __shfl_xor(ax,  off, 64);
            ay  += __shfl_xor(ay,  off, 64);
            az  += __shfl_xor(az,  off, 64);
            aw  += __shfl_xor(aw,  off, 64);
            den += __shfl_xor(den, off, 64);
        }
        const float rden = 1.0f / (den + 1e-16f);
        const float4 bc = *(const float4*)(bias_conv + 4 * l);
        float rx = fmaf(ax, rden, bc.x); rx = rx > 0.f ? rx : 0.f;
        float ry = fmaf(ay, rden, bc.y); ry = ry > 0.f ? ry : 0.f;
        float rz = fmaf(az, rden, bc.z); rz = rz > 0.f ? rz : 0.f;
        float rw = fmaf(aw, rden, bc.w); rw = rw > 0.f ? rw : 0.f;
        if (g == 0) {
            v[wv][4 * l + 0] = rx;
            v[wv][4 * l + 1] = ry;
            v[wv][4 * l + 2] = rz;
            v[wv][4 * l + 3] = rw;
        }
    }
    __syncthreads();

    if (valid && lane < OUT_C) {
        float o = b_lin[lane];
#pragma unroll
        for (int c = 0; c < HID_C; ++c)
            o = fmaf(v[wv][c], W_lin[c * OUT_C + lane], o);
        out[(long)node * OUT_C + lane] = o;
    }
}

// ---------------------------------------------------------------------------
extern "C" void kernel_launch(void* const* d_in, const int* in_sizes, int n_in,
                              void* d_out, int out_size, void* d_ws, size_t ws_size,
                              hipStream_t stream) {
    const float* x         = (const float*)d_in[0];
    const int*   ei        = (const int*)d_in[1];
    const float* W         = (const float*)d_in[2];
    const float* att_src   = (const float*)d_in[3];
    const float* att_dst   = (const float*)d_in[4];
    const float* bias_conv = (const float*)d_in[5];
    const float* W_lin     = (const float*)d_in[6];
    const float* b_lin     = (const float*)d_in[7];
    float*       out       = (float*)d_out;

    const int n_nodes = in_sizes[0] / IN_C;     // 50000
    const int E       = in_sizes[1] / 2;        // 800000
    const int total_edges = E + n_nodes;        // incl. self-loops
    const int nb = (n_nodes + 1023) / 1024;     // scan blocks (49)

    // workspace layout (hb first: 8B-aligned ushort4 loads)
    __hip_bfloat16* hb = (__hip_bfloat16*)d_ws;              // N*64 bf16
    float* a_src = (float*)(hb + (long)n_nodes * HID_C);     // N f
    float* a_dst = a_src + n_nodes;                          // N f
    int*   deg    = (int*)(a_dst + n_nodes);                 // N i
    int*   rowptr = deg    + n_nodes;                        // N+1 i
    int*   cursor = rowptr + n_nodes + 1;                    // N i
    int*   bsum   = cursor + n_nodes;                        // 64 i
    int*   boff   = bsum   + 64;                             // 64 i
    int*   srt    = boff   + 64;                             // E+N i

    // 1) deg = 1 (self loops)
    init_deg_kernel<<<(n_nodes + 255) / 256, 256, 0, stream>>>(deg, n_nodes);

    // 2) histogram over real edge destinations
    hist_kernel<<<(E + 255) / 256, 256, 0, stream>>>(ei + E, E, deg);

    // 3) parallel scan -> rowptr, cursor
    scan1_kernel<<<nb, 1024, 0, stream>>>(deg, rowptr, bsum, n_nodes);
    scan2_kernel<<<1, 64, 0, stream>>>(bsum, boff, nb);
    scan3_kernel<<<(n_nodes + 255) / 256, 256, 0, stream>>>(
        rowptr, cursor, boff, n_nodes, total_edges);

    // 4) node GEMM + logits (independent of 1-3)
    node_gemm_kernel<<<768, 256, 0, stream>>>(
        x, W, att_src, att_dst, hb, a_src, a_dst, n_nodes);

    // 5) bucket fill
    fill_kernel<<<(total_edges + 255) / 256, 256, 0, stream>>>(
        ei, E, n_nodes, cursor, srt);

    // 6) fused aggregation + epilogue
    agg_kernel<<<(n_nodes + 3) / 4, 256, 0, stream>>>(
        rowptr, srt, hb, a_src, a_dst, bias_conv, W_lin, b_lin, out, n_nodes);
}

// Round 4
// 257.372 us; speedup vs baseline: 1.7117x; 1.0502x over previous
//
#include <hip/hip_runtime.h>
#include <hip/hip_bf16.h>

#define IN_C  128
#define HID_C 64
#define OUT_C 32
#define NEG_SLOPE 0.2f

// ---------------------------------------------------------------------------
// Kernel 1: zero deg
// ---------------------------------------------------------------------------
__global__ void zero_deg_kernel(int* __restrict__ deg, int n) {
    int i = blockIdx.x * blockDim.x + threadIdx.x;
    if (i < n) deg[i] = 0;
}

// ---------------------------------------------------------------------------
// Kernel 2: h = x @ W per node + attention logits; h stored as bf16.
// W column in 128 VGPRs per wave; grid-stride over node pairs.
// ---------------------------------------------------------------------------
__device__ __forceinline__ float lane_bcast(float v, int k) {
    return __int_as_float(__builtin_amdgcn_readlane(__float_as_int(v), k));
}

__global__ __launch_bounds__(256) void node_gemm_kernel(
    const float* __restrict__ x, const float* __restrict__ W,
    const float* __restrict__ att_src, const float* __restrict__ att_dst,
    __hip_bfloat16* __restrict__ hb,
    float* __restrict__ a_src, float* __restrict__ a_dst,
    int n_nodes)
{
    const int lane = threadIdx.x & 63;
    const int gwave = (blockIdx.x * 256 + threadIdx.x) >> 6;
    const int nwaves = gridDim.x * 4;

    float wr[IN_C];
#pragma unroll
    for (int k = 0; k < IN_C; ++k) wr[k] = W[k * HID_C + lane];
    const float asl = att_src[lane];
    const float adl = att_dst[lane];

    for (int base = gwave * 2; base < n_nodes; base += nwaves * 2) {
        const int n0 = base;
        const int n1 = base + 1;
        const bool v1 = n1 < n_nodes;
        const float* x0 = x + (long)n0 * IN_C;
        const float* x1 = x + (long)(v1 ? n1 : n0) * IN_C;
        const float a0 = x0[lane], b0 = x0[lane + 64];
        const float a1 = x1[lane], b1 = x1[lane + 64];

        float acc0 = 0.f, acc1 = 0.f, acc0b = 0.f, acc1b = 0.f;
#pragma unroll
        for (int k = 0; k < 64; ++k) {
            acc0  = fmaf(lane_bcast(a0, k), wr[k],      acc0);
            acc1  = fmaf(lane_bcast(a1, k), wr[k],      acc1);
            acc0b = fmaf(lane_bcast(b0, k), wr[64 + k], acc0b);
            acc1b = fmaf(lane_bcast(b1, k), wr[64 + k], acc1b);
        }
        const float h0 = acc0 + acc0b;
        const float h1 = acc1 + acc1b;

        hb[(long)n0 * HID_C + lane] = __float2bfloat16(h0);
        if (v1) hb[(long)n1 * HID_C + lane] = __float2bfloat16(h1);

        float vs0 = h0 * asl, vd0 = h0 * adl;
        float vs1 = h1 * asl, vd1 = h1 * adl;
#pragma unroll
        for (int off = 32; off > 0; off >>= 1) {
            vs0 += __shfl_xor(vs0, off, 64);
            vd0 += __shfl_xor(vd0, off, 64);
            vs1 += __shfl_xor(vs1, off, 64);
            vd1 += __shfl_xor(vd1, off, 64);
        }
        if (lane == 0) {
            a_src[n0] = vs0; a_dst[n0] = vd0;
            if (v1) { a_src[n1] = vs1; a_dst[n1] = vd1; }
        }
    }
}

// ---------------------------------------------------------------------------
// Kernel 3: per-edge softmax weight (coalesced edge order) + dst histogram
// ---------------------------------------------------------------------------
__global__ void histw_kernel(const int* __restrict__ ei, int E,
                             const float* __restrict__ a_src,
                             const float* __restrict__ a_dst,
                             float* __restrict__ w, int* __restrict__ deg)
{
    int i = blockIdx.x * blockDim.x + threadIdx.x;
    if (i >= E) return;
    const int s = ei[i];
    const int d = ei[E + i];
    float e = a_src[s] + a_dst[d];
    e = (e >= 0.f) ? e : NEG_SLOPE * e;
    w[i] = __expf(e);
    atomicAdd(deg + d, 1);
}

// ---------------------------------------------------------------------------
// Scan phase A: per-block exclusive scan of (deg[i]+1), emit block sums
// (+1 folds in the self-loop)
// ---------------------------------------------------------------------------
__global__ __launch_bounds__(1024) void scan1_kernel(
    const int* __restrict__ deg, int* __restrict__ rowptr,
    int* __restrict__ bsum, int n)
{
    __shared__ int sh[1024];
    const int t = threadIdx.x;
    const int i = blockIdx.x * 1024 + t;
    int val = (i < n) ? deg[i] + 1 : 0;
    sh[t] = val;
    __syncthreads();
#pragma unroll
    for (int off = 1; off < 1024; off <<= 1) {
        int add = (t >= off) ? sh[t - off] : 0;
        __syncthreads();
        sh[t] += add;
        __syncthreads();
    }
    if (i < n) rowptr[i] = sh[t] - val;       // exclusive
    if (t == 1023) bsum[blockIdx.x] = sh[1023];
}

// ---------------------------------------------------------------------------
// Scan phase B: single wave scans the block sums (nb <= 64)
// ---------------------------------------------------------------------------
__global__ __launch_bounds__(64) void scan2_kernel(
    const int* __restrict__ bsum, int* __restrict__ boff, int nb)
{
    const int t = threadIdx.x;
    int v = (t < nb) ? bsum[t] : 0;
    int incl = v;
#pragma unroll
    for (int off = 1; off < 64; off <<= 1) {
        int u = __shfl_up(incl, off, 64);
        if (t >= off) incl += u;
    }
    boff[t] = incl - v;                       // exclusive
}

// ---------------------------------------------------------------------------
// Scan phase C: add block offsets, mirror into cursor, cap rowptr[n]
// ---------------------------------------------------------------------------
__global__ void scan3_kernel(int* __restrict__ rowptr, int* __restrict__ cursor,
                             const int* __restrict__ boff, int n, int total)
{
    int i = blockIdx.x * blockDim.x + threadIdx.x;
    if (i < n) {
        int r = rowptr[i] + boff[i >> 10];
        rowptr[i] = r;
        cursor[i] = r;
    }
    if (i == 0) rowptr[n] = total;
}

// ---------------------------------------------------------------------------
// Kernel 5: bucket-fill packed (src, w) records (8B scatter)
// ---------------------------------------------------------------------------
__global__ void fill_kernel(const int* __restrict__ ei, int E, int n_nodes,
                            const float* __restrict__ w,
                            const float* __restrict__ a_src,
                            const float* __restrict__ a_dst,
                            int* __restrict__ cursor, float2* __restrict__ srtw)
{
    long i = (long)blockIdx.x * blockDim.x + threadIdx.x;
    long total = (long)E + n_nodes;
    if (i >= total) return;
    int s, d; float ww;
    if (i < E) {
        s = ei[i]; d = ei[E + i]; ww = w[i];
    } else {
        s = d = (int)(i - E);
        float e = a_src[s] + a_dst[s];          // coalesced (s == thread idx - E)
        e = (e >= 0.f) ? e : NEG_SLOPE * e;
        ww = __expf(e);
    }
    int pos = atomicAdd(cursor + d, 1);
    srtw[pos] = make_float2(__int_as_float(s), ww);
}

// ---------------------------------------------------------------------------
// Kernel 6: fused aggregation + normalize + bias/relu + final linear.
// One wave per dst node. lane = g*8 + l: g = edge slot (8 edges in flight),
// l = channel octet (16B uint4 bf16 load; 8 lanes cover the 128B row).
// ---------------------------------------------------------------------------
__device__ __forceinline__ float bflo(unsigned int u) {
    return __uint_as_float(u << 16);
}
__device__ __forceinline__ float bfhi(unsigned int u) {
    return __uint_as_float(u & 0xffff0000u);
}

__global__ __launch_bounds__(256) void agg_kernel(
    const int* __restrict__ rowptr, const float2* __restrict__ srtw,
    const __hip_bfloat16* __restrict__ hb,
    const float* __restrict__ bias_conv,
    const float* __restrict__ W_lin, const float* __restrict__ b_lin,
    float* __restrict__ out, int n_nodes)
{
    __shared__ float v[4][HID_C];
    const int wv   = threadIdx.x >> 6;
    const int lane = threadIdx.x & 63;
    const int g    = lane >> 3;     // edge slot 0..7
    const int l    = lane & 7;      // channel octet
    const int node = blockIdx.x * 4 + wv;
    const bool valid = node < n_nodes;

    if (valid) {
        const int beg = rowptr[node];
        const int fin = rowptr[node + 1];
        float a0=0.f,a1=0.f,a2=0.f,a3=0.f,a4=0.f,a5=0.f,a6=0.f,a7=0.f,den=0.f;

        for (int j = beg; j < fin; j += 8) {
            const int  jg  = j + g;
            const bool act = jg < fin;
            const int  jc  = act ? jg : fin - 1;     // deg >= 1 always
            const float2 p = srtw[jc];
            const int   s  = __float_as_int(p.x);
            const float ww = act ? p.y : 0.f;
            const uint4 hv = *(const uint4*)((const unsigned short*)hb
                                             + (long)s * HID_C + 8 * l);
            den += ww;
            a0 = fmaf(ww, bflo(hv.x), a0);
            a1 = fmaf(ww, bfhi(hv.x), a1);
            a2 = fmaf(ww, bflo(hv.y), a2);
            a3 = fmaf(ww, bfhi(hv.y), a3);
            a4 = fmaf(ww, bflo(hv.z), a4);
            a5 = fmaf(ww, bfhi(hv.z), a5);
            a6 = fmaf(ww, bflo(hv.w), a6);
            a7 = fmaf(ww, bfhi(hv.w), a7);
        }
        // reduce across the 8 edge slots (lanes differing in bits 3..5)
#pragma unroll
        for (int off = 8; off <= 32; off <<= 1) {
            a0 += __shfl_xor(a0, off, 64);
            a1 += __shfl_xor(a1, off, 64);
            a2 += __shfl_xor(a2, off, 64);
            a3 += __shfl_xor(a3, off, 64);
            a4 += __shfl_xor(a4, off, 64);
            a5 += __shfl_xor(a5, off, 64);
            a6 += __shfl_xor(a6, off, 64);
            a7 += __shfl_xor(a7, off, 64);
            den += __shfl_xor(den, off, 64);
        }
        if (g == 0) {
            const float rden = 1.0f / (den + 1e-16f);
            const float4 bc0 = *(const float4*)(bias_conv + 8 * l);
            const float4 bc1 = *(const float4*)(bias_conv + 8 * l + 4);
            float r;
            r = fmaf(a0, rden, bc0.x); v[wv][8*l+0] = r > 0.f ? r : 0.f;
            r = fmaf(a1, rden, bc0.y); v[wv][8*l+1] = r > 0.f ? r : 0.f;
            r = fmaf(a2, rden, bc0.z); v[wv][8*l+2] = r > 0.f ? r : 0.f;
            r = fmaf(a3, rden, bc0.w); v[wv][8*l+3] = r > 0.f ? r : 0.f;
            r = fmaf(a4, rden, bc1.x); v[wv][8*l+4] = r > 0.f ? r : 0.f;
            r = fmaf(a5, rden, bc1.y); v[wv][8*l+5] = r > 0.f ? r : 0.f;
            r = fmaf(a6, rden, bc1.z); v[wv][8*l+6] = r > 0.f ? r : 0.f;
            r = fmaf(a7, rden, bc1.w); v[wv][8*l+7] = r > 0.f ? r : 0.f;
        }
    }
    __syncthreads();

    if (valid && lane < OUT_C) {
        float o = b_lin[lane];
#pragma unroll
        for (int c = 0; c < HID_C; ++c)
            o = fmaf(v[wv][c], W_lin[c * OUT_C + lane], o);
        out[(long)node * OUT_C + lane] = o;
    }
}

// ---------------------------------------------------------------------------
extern "C" void kernel_launch(void* const* d_in, const int* in_sizes, int n_in,
                              void* d_out, int out_size, void* d_ws, size_t ws_size,
                              hipStream_t stream) {
    const float* x         = (const float*)d_in[0];
    const int*   ei        = (const int*)d_in[1];
    const float* W         = (const float*)d_in[2];
    const float* att_src   = (const float*)d_in[3];
    const float* att_dst   = (const float*)d_in[4];
    const float* bias_conv = (const float*)d_in[5];
    const float* W_lin     = (const float*)d_in[6];
    const float* b_lin     = (const float*)d_in[7];
    float*       out       = (float*)d_out;

    const int n_nodes = in_sizes[0] / IN_C;     // 50000
    const int E       = in_sizes[1] / 2;        // 800000
    const int total_edges = E + n_nodes;        // incl. self-loops
    const int nb = (n_nodes + 1023) / 1024;     // scan blocks (49)

    // workspace layout (16B-aligned hb first, then 8B srtw)
    __hip_bfloat16* hb = (__hip_bfloat16*)d_ws;              // N*64 bf16
    float2* srtw  = (float2*)(hb + (long)n_nodes * HID_C);   // (E+N)*8B
    float* a_src  = (float*)(srtw + total_edges);            // N f
    float* a_dst  = a_src + n_nodes;                         // N f
    float* w      = a_dst + n_nodes;                         // E f
    int*   deg    = (int*)(w + E);                           // N i
    int*   rowptr = deg    + n_nodes;                        // N+1 i
    int*   cursor = rowptr + n_nodes + 1;                    // N i
    int*   bsum   = cursor + n_nodes;                        // 64 i
    int*   boff   = bsum   + 64;                             // 64 i

    // 1) deg = 0
    zero_deg_kernel<<<(n_nodes + 255) / 256, 256, 0, stream>>>(deg, n_nodes);

    // 2) node GEMM + logits
    node_gemm_kernel<<<768, 256, 0, stream>>>(
        x, W, att_src, att_dst, hb, a_src, a_dst, n_nodes);

    // 3) per-edge weights + histogram
    histw_kernel<<<(E + 255) / 256, 256, 0, stream>>>(ei, E, a_src, a_dst, w, deg);

    // 4) parallel scan -> rowptr, cursor (self-loop +1 folded in)
    scan1_kernel<<<nb, 1024, 0, stream>>>(deg, rowptr, bsum, n_nodes);
    scan2_kernel<<<1, 64, 0, stream>>>(bsum, boff, nb);
    scan3_kernel<<<(n_nodes + 255) / 256, 256, 0, stream>>>(
        rowptr, cursor, boff, n_nodes, total_edges);

    // 5) bucket fill (8B packed records)
    fill_kernel<<<(total_edges + 255) / 256, 256, 0, stream>>>(
        ei, E, n_nodes, w, a_src, a_dst, cursor, srtw);

    // 6) fused aggregation + epilogue
    agg_kernel<<<(n_nodes + 3) / 4, 256, 0, stream>>>(
        rowptr, srtw, hb, bias_conv, W_lin, b_lin, out, n_nodes);
}